// Round 14
// baseline (104.459 us; speedup 1.0000x reference)
//
#include <hip/hip_runtime.h>
#include <hip/hip_bf16.h>

typedef __attribute__((ext_vector_type(8))) short bf16x8;
typedef __attribute__((ext_vector_type(4))) short bf16x4;
typedef __attribute__((ext_vector_type(4))) float f32x4;
typedef __attribute__((ext_vector_type(16))) float f32x16;
typedef __attribute__((ext_vector_type(2))) unsigned u32x2;

#define NB 4
#define NL 2048
#define NH 16
#define NE 64
#define HE (NH*NE)
#define QW 32
#define QBLK 128
#define NQT (NL/QBLK)      // 16
#define NPAIR (NQT/2)      // 8
#define NBH 64
#define NKT 32             // kv64 tiles per (b,h)
#define TILE_IMG 16384     // 8KB K + 8KB V^T per (bh, kv-tile)
#define IMG_BYTES ((size_t)NBH * NKT * TILE_IMG)          // 32 MB
#define OPART_HALF ((size_t)NBH * NL * NE * 2)            // 16 MB bf16
#define LPART_HALF ((size_t)NBH * NL * 4)                 // 512 KB f32
#define WS_NEED  IMG_BYTES                                 // image path
#define WS_SPLIT (IMG_BYTES + 2*OPART_HALF + 2*LPART_HALF) // ~65 MB
#define QSCALE (0.125f * 1.44269504088896340736f)  // 1/sqrt(64) * log2(e)

__device__ __forceinline__ unsigned pk2(float a, float b) {
  float2 t; t.x = a; t.y = b;
  __hip_bfloat162 hh = __float22bfloat162_rn(t);    // v_cvt_pk_bf16_f32
  union { __hip_bfloat162 h; unsigned u; } v; v.h = hh;
  return v.u;                                        // a lo16, b hi16
}
__device__ __forceinline__ float bf2f(unsigned short x) {
  union { unsigned u; float f; } t; t.u = ((unsigned)x) << 16; return t.f;
}
__device__ __forceinline__ void pswap(unsigned &a, unsigned &b) {
  auto r = __builtin_amdgcn_permlane32_swap(a, b, false, false);
  a = r[0]; b = r[1];
}
#define SWZ(row,col) ((row)*128 + ((col) ^ ((((row) ^ ((row)>>2)) & 7) << 4)))

__device__ __forceinline__ void cp16(unsigned char* lds, const unsigned char* g) {
  __builtin_amdgcn_global_load_lds(
      (const __attribute__((address_space(1))) unsigned int*)g,
      (__attribute__((address_space(3))) unsigned int*)lds, 16, 0, 0);
}

// ---------------- prologue: build bf16 staged tile images in ws ----------------
__global__ __launch_bounds__(256) void fa_stage(
    const float* __restrict__ K, const float* __restrict__ V,
    unsigned char* __restrict__ img)
{
  const int tid = threadIdx.x;
  const int bid = blockIdx.x;
  const int bh  = bid >> 5;
  const int t0  = bid & 31;
  const int h = bh & (NH-1), b = bh >> 4;
  const size_t base = ((size_t)b * NL * NH + h) * NE + (size_t)(t0 * 64) * HE;
  unsigned char* kimg = img + (size_t)(bh * NKT + t0) * TILE_IMG;
  unsigned char* vimg = kimg + 8192;
  #pragma unroll
  for (int rep = 0; rep < 2; ++rep) {
    const int idx = rep * 256 + tid;
    const int row = idx >> 3, gr = idx & 7;
    const float* kp = K + base + (size_t)row * HE + gr * 8;
    f32x4 a0 = *(const f32x4*)kp;
    f32x4 a1 = *(const f32x4*)(kp + 4);
    union { unsigned u[4]; bf16x8 v; } w;
    w.u[0] = pk2(a0[0], a0[1]); w.u[1] = pk2(a0[2], a0[3]);
    w.u[2] = pk2(a1[0], a1[1]); w.u[3] = pk2(a1[2], a1[3]);
    *(bf16x8*)(kimg + SWZ(row, gr * 16)) = w.v;
  }
  const int trow = tid >> 4, tcol = (tid & 15) * 4, sq = trow * 4;
  f32x4 vr[4];
  #pragma unroll
  for (int i = 0; i < 4; ++i)
    vr[i] = *(const f32x4*)(V + base + (size_t)(sq + i) * HE + tcol);
  #pragma unroll
  for (int j = 0; j < 4; ++j) {
    const int er = tcol + j;
    union { unsigned u[2]; bf16x4 v; } w;
    w.u[0] = pk2(vr[0][j], vr[1][j]);
    w.u[1] = pk2(vr[2][j], vr[3][j]);
    *(bf16x4*)(vimg + SWZ(er, sq * 2)) = w.v;
  }
}

// ---- shared step machinery (expects locals: l_run, qf, addr4, qb, qg, nt,
//      src_pf, wb, oacc2, k_lds, v_lds) ----
#define PACK(SC, PA0, PA1)                                                     \
      l_run += (((SC[0]+SC[1])+(SC[2]+SC[3]))+((SC[4]+SC[5])+(SC[6]+SC[7])))   \
             + (((SC[8]+SC[9])+(SC[10]+SC[11]))+((SC[12]+SC[13])+(SC[14]+SC[15])));\
      {                                                                        \
        unsigned c0 = pk2(SC[0],SC[1]),   c1 = pk2(SC[2],SC[3]);               \
        unsigned c2 = pk2(SC[4],SC[5]),   c3 = pk2(SC[6],SC[7]);               \
        unsigned c4 = pk2(SC[8],SC[9]),   c5 = pk2(SC[10],SC[11]);             \
        unsigned c6 = pk2(SC[12],SC[13]), c7 = pk2(SC[14],SC[15]);             \
        pswap(c0, c2);  pswap(c1, c3);                                         \
        pswap(c4, c6);  pswap(c5, c7);                                         \
        PA0.u[0]=c0; PA0.u[1]=c1; PA0.u[2]=c2; PA0.u[3]=c3;                    \
        PA1.u[0]=c4; PA1.u[1]=c5; PA1.u[2]=c6; PA1.u[3]=c7;                    \
      }

#define SMPACK(SC, PA0, PA1)                                                   \
      _Pragma("unroll")                                                        \
      for (int r = 0; r < 16; ++r) SC[r] = exp2f(SC[r]);                       \
      PACK(SC, PA0, PA1)

#define STEPG(IT, BUF, STRIDE)                                                 \
    {                                                                          \
      asm volatile("s_waitcnt vmcnt(0)" ::: "memory");                         \
      __builtin_amdgcn_sched_barrier(0);                                       \
      __builtin_amdgcn_s_barrier();                                            \
      __builtin_amdgcn_sched_barrier(0);                                       \
      if ((IT) + (STRIDE) < nt) {                                              \
        cp16(&k_lds[(BUF)^1][0] + wb,        src_pf);                          \
        cp16(&k_lds[(BUF)^1][0] + 4096 + wb, src_pf + 4096);                   \
        cp16(&v_lds[(BUF)^1][0] + wb,        src_pf + 8192);                   \
        cp16(&v_lds[(BUF)^1][0] + 4096 + wb, src_pf + 12288);                  \
        src_pf += (size_t)(STRIDE) * TILE_IMG;                                 \
      }                                                                        \
      const int kv0 = (IT)*64;                                                 \
      if (kv0 + 63 <= qb) {                                                    \
        f32x16 sc0 = (f32x16)0.0f, sc1 = (f32x16)0.0f;                         \
        _Pragma("unroll")                                                      \
        for (int ks = 0; ks < 4; ++ks) {                                       \
          bf16x8 af0 = *(const bf16x8*)(&k_lds[BUF][0] + addr4[ks]);           \
          bf16x8 af1 = *(const bf16x8*)(&k_lds[BUF][0] + addr4[ks] + 4096);    \
          sc0 = __builtin_amdgcn_mfma_f32_32x32x16_bf16(af0, qf[ks], sc0,0,0,0);\
          sc1 = __builtin_amdgcn_mfma_f32_32x32x16_bf16(af1, qf[ks], sc1,0,0,0);\
        }                                                                      \
        union { unsigned u[4]; bf16x8 v; } a00, a01, a10, a11;                 \
        SMPACK(sc0, a00, a01)                                                  \
        SMPACK(sc1, a10, a11)                                                  \
        _Pragma("unroll")                                                      \
        for (int dt = 0; dt < 2; ++dt) {                                       \
          bf16x8 v00 = *(const bf16x8*)(&v_lds[BUF][0] + addr4[0] + dt*4096);  \
          bf16x8 v01 = *(const bf16x8*)(&v_lds[BUF][0] + addr4[1] + dt*4096);  \
          bf16x8 v10 = *(const bf16x8*)(&v_lds[BUF][0] + addr4[2] + dt*4096);  \
          bf16x8 v11 = *(const bf16x8*)(&v_lds[BUF][0] + addr4[3] + dt*4096);  \
          oacc2[0][dt] = __builtin_amdgcn_mfma_f32_32x32x16_bf16(              \
              v00, a00.v, oacc2[0][dt], 0, 0, 0);                              \
          oacc2[1][dt] = __builtin_amdgcn_mfma_f32_32x32x16_bf16(              \
              v10, a10.v, oacc2[1][dt], 0, 0, 0);                              \
          oacc2[0][dt] = __builtin_amdgcn_mfma_f32_32x32x16_bf16(              \
              v01, a01.v, oacc2[0][dt], 0, 0, 0);                              \
          oacc2[1][dt] = __builtin_amdgcn_mfma_f32_32x32x16_bf16(              \
              v11, a11.v, oacc2[1][dt], 0, 0, 0);                              \
        }                                                                      \
      } else {                                                                 \
        _Pragma("unroll")                                                      \
        for (int sub = 0; sub < 2; ++sub) {                                    \
          const int kv0s = kv0 + sub*32;                                       \
          if (kv0s <= qb + QW - 1) {                                           \
            f32x16 sc = (f32x16)0.0f;                                          \
            _Pragma("unroll")                                                  \
            for (int ks = 0; ks < 4; ++ks) {                                   \
              bf16x8 af = *(const bf16x8*)(&k_lds[BUF][0] + addr4[ks] + sub*4096);\
              sc = __builtin_amdgcn_mfma_f32_32x32x16_bf16(af, qf[ks], sc,0,0,0);\
            }                                                                  \
            _Pragma("unroll")                                                  \
            for (int r = 0; r < 16; ++r) {                                     \
              const int kvg = kv0s + (r&3) + 8*(r>>2) + 4*hi;                  \
              sc[r] = (kvg > qg) ? 0.0f : exp2f(sc[r]);                        \
            }                                                                  \
            union { unsigned u[4]; bf16x8 v; } pa0, pa1;                       \
            PACK(sc, pa0, pa1)                                                 \
            _Pragma("unroll")                                                  \
            for (int dt = 0; dt < 2; ++dt) {                                   \
              _Pragma("unroll")                                                \
              for (int ks2 = 0; ks2 < 2; ++ks2) {                              \
                bf16x8 av = *(const bf16x8*)(&v_lds[BUF][0] +                  \
                    addr4[sub*2 + ks2] + dt*4096);                             \
                oacc2[sub][dt] = __builtin_amdgcn_mfma_f32_32x32x16_bf16(      \
                    av, ks2 ? pa1.v : pa0.v, oacc2[sub][dt], 0, 0, 0);         \
              }                                                                \
            }                                                                  \
          }                                                                    \
        }                                                                      \
      }                                                                        \
    }

// common per-q-tile prologue (Q frags + acc init)
#define QTILE_SETUP()                                                          \
    bf16x8 qf[4];                                                              \
    {                                                                          \
      const float* qp = Qb + (size_t)(qb + ln) * HE + hi * 8;                  \
      _Pragma("unroll")                                                        \
      for (int ks = 0; ks < 4; ++ks) {                                         \
        f32x4 a0 = *(const f32x4*)(qp + ks*16);                                \
        f32x4 a1 = *(const f32x4*)(qp + ks*16 + 4);                            \
        union { unsigned u[4]; bf16x8 v; } f;                                  \
        f.u[0] = pk2(a0[0]*QSCALE, a0[1]*QSCALE);                              \
        f.u[1] = pk2(a0[2]*QSCALE, a0[3]*QSCALE);                              \
        f.u[2] = pk2(a1[0]*QSCALE, a1[1]*QSCALE);                              \
        f.u[3] = pk2(a1[2]*QSCALE, a1[3]*QSCALE);                              \
        qf[ks] = f.v;                                                          \
      }                                                                        \
    }                                                                          \
    f32x16 oacc2[2][2];                                                        \
    oacc2[0][0] = (f32x16)0.0f; oacc2[0][1] = (f32x16)0.0f;                    \
    oacc2[1][0] = (f32x16)0.0f; oacc2[1][1] = (f32x16)0.0f;                    \
    float l_run = 0.0f;

// ---------------- split-K main: each block does one kv-parity of a pair ----------------
__global__ __launch_bounds__(256, 2) void fa_split(
    const float* __restrict__ Q, const unsigned char* __restrict__ img,
    unsigned short* __restrict__ opart, float* __restrict__ lpart)
{
  __shared__ unsigned char k_lds[2][8192];
  __shared__ unsigned char v_lds[2][8192];

  const int tid  = threadIdx.x;
  const int lane = tid & 63;
  const int wid  = tid >> 6;
  const int hi   = lane >> 5;
  const int ln   = lane & 31;

  const int bidp = blockIdx.x;
  const int lb   = (bidp & 7) * 128 + (bidp >> 3);  // XCD chunks of 128
  const int half = lb & 1;
  const int pair = (lb >> 1) & 7;
  const int bh   = lb >> 4;
  const int h    = bh & (NH-1);
  const int b    = bh >> 4;

  const size_t base = ((size_t)b * NL * NH + h) * NE;
  const float* Qb = Q + base;
  const unsigned char* bimg = img + (size_t)bh * NKT * TILE_IMG;
  unsigned short* op_half = opart + (size_t)half * (OPART_HALF/2);
  float*          l_half  = lpart + (size_t)half * (LPART_HALF/4);

  int addr4[4];
  {
    const int F = ((ln ^ (ln >> 2)) & 7) << 4;
    #pragma unroll
    for (int j = 0; j < 4; ++j) addr4[j] = ln*128 + ((j*32 + hi*16) ^ F);
  }
  const int wb = wid << 10;

  #pragma unroll 1
  for (int hf = 0; hf < 2; ++hf) {
    const int qt = hf ? (NQT - 1 - pair) : pair;
    const int q0 = qt * QBLK;
    const int qb = q0 + wid * QW;
    const int nt = qt * 2 + 2;
    const int cnt = nt >> 1;            // steps for this parity (= qt+1)
    const int qg = qb + ln;

    QTILE_SETUP()

    // protect LDS reuse across hf / prologue overwrite
    __builtin_amdgcn_s_barrier();
    const unsigned char* src_pf = bimg + (size_t)half * TILE_IMG + (size_t)tid * 16;
    cp16(&k_lds[0][0] + wb,        src_pf);
    cp16(&k_lds[0][0] + 4096 + wb, src_pf + 4096);
    cp16(&v_lds[0][0] + wb,        src_pf + 8192);
    cp16(&v_lds[0][0] + 4096 + wb, src_pf + 12288);
    src_pf += 2 * TILE_IMG;

    int it0 = half;
    #pragma unroll 1
    for (int jp = 0; jp + 2 <= cnt; jp += 2) {
      STEPG(it0, 0, 2)
      STEPG(it0 + 2, 1, 2)
      it0 += 4;
    }
    if (cnt & 1) STEPG(it0, 0, 2)

    // ---- epilogue: store UNNORMALIZED bf16 partial O + f32 partial l ----
    const float l_tot = l_run + __shfl_xor(l_run, 32);
    const size_t rowi = (size_t)bh * NL + (qb + ln);
    l_half[rowi] = l_tot;
    unsigned short* po = op_half + rowi * 64;
    #pragma unroll
    for (int dt = 0; dt < 2; ++dt)
      #pragma unroll
      for (int rq = 0; rq < 4; ++rq) {
        const float e0 = oacc2[0][dt][rq*4+0]+oacc2[1][dt][rq*4+0];
        const float e1 = oacc2[0][dt][rq*4+1]+oacc2[1][dt][rq*4+1];
        const float e2 = oacc2[0][dt][rq*4+2]+oacc2[1][dt][rq*4+2];
        const float e3 = oacc2[0][dt][rq*4+3]+oacc2[1][dt][rq*4+3];
        u32x2 w; w[0] = pk2(e0, e1); w[1] = pk2(e2, e3);
        *(u32x2*)(po + dt*32 + 8*rq + 4*hi) = w;
      }
  }
}

// ---------------- merge: O = (A+B)/(lA+lB), remap to [b][l][h][d] ----------------
__global__ __launch_bounds__(256) void fa_merge(
    const unsigned short* __restrict__ opart, const float* __restrict__ lpart,
    float* __restrict__ O)
{
  const size_t p = (size_t)blockIdx.x * 256 + threadIdx.x;  // f32x4 group id
  const int d4 = (int)(p & 15);
  const int l  = (int)((p >> 4) & (NL-1));
  const int hh = (int)((p >> 15) & (NH-1));
  const int bb = (int)(p >> 19);
  const size_t rowi = (size_t)(bb*NH + hh) * NL + l;
  const float inv = 1.0f / (lpart[rowi] + lpart[(LPART_HALF/4) + rowi]);
  const unsigned short* pa = opart + rowi*64 + d4*4;
  const unsigned short* pb = pa + (OPART_HALF/2);
  bf16x4 a = *(const bf16x4*)pa;
  bf16x4 c = *(const bf16x4*)pb;
  f32x4 w;
  w[0] = (bf2f((unsigned short)a[0]) + bf2f((unsigned short)c[0])) * inv;
  w[1] = (bf2f((unsigned short)a[1]) + bf2f((unsigned short)c[1])) * inv;
  w[2] = (bf2f((unsigned short)a[2]) + bf2f((unsigned short)c[2])) * inv;
  w[3] = (bf2f((unsigned short)a[3]) + bf2f((unsigned short)c[3])) * inv;
  *(f32x4*)(O + ((((size_t)bb*NL + l)*NH + hh)*NE + d4*4)) = w;
}

// ---------------- image path (R13, proven 89us) ----------------
__global__ __launch_bounds__(256, 2) void fa_fwd(
    const float* __restrict__ Q, const unsigned char* __restrict__ img,
    float* __restrict__ O)
{
  __shared__ unsigned char k_lds[2][8192];
  __shared__ unsigned char v_lds[2][8192];

  const int tid  = threadIdx.x;
  const int lane = tid & 63;
  const int wid  = tid >> 6;
  const int hi   = lane >> 5;
  const int ln   = lane & 31;

  const int bidp = blockIdx.x;
  const int lb   = (bidp & 7) * 64 + (bidp >> 3);
  const int pair = lb & 7;
  const int bh   = lb >> 3;
  const int h    = bh & (NH-1);
  const int b    = bh >> 4;

  const size_t base = ((size_t)b * NL * NH + h) * NE;
  const float* Qb = Q + base;
  float*       Ob = O + base;
  const unsigned char* bimg = img + (size_t)bh * NKT * TILE_IMG;

  int addr4[4];
  {
    const int F = ((ln ^ (ln >> 2)) & 7) << 4;
    #pragma unroll
    for (int j = 0; j < 4; ++j) addr4[j] = ln*128 + ((j*32 + hi*16) ^ F);
  }
  const int wb = wid << 10;

  #pragma unroll 1
  for (int hf = 0; hf < 2; ++hf) {
    const int qt = hf ? (NQT - 1 - pair) : pair;
    const int q0 = qt * QBLK;
    const int qb = q0 + wid * QW;
    const int nt = qt * 2 + 2;                     // always even
    const int qg = qb + ln;

    QTILE_SETUP()

    __builtin_amdgcn_s_barrier();
    const unsigned char* src_pf = bimg + (size_t)tid * 16;
    cp16(&k_lds[0][0] + wb,        src_pf);
    cp16(&k_lds[0][0] + 4096 + wb, src_pf + 4096);
    cp16(&v_lds[0][0] + wb,        src_pf + 8192);
    cp16(&v_lds[0][0] + 4096 + wb, src_pf + 12288);
    src_pf += TILE_IMG;

    #pragma unroll 1
    for (int ip = 0; ip < nt; ip += 2) {
      STEPG(ip, 0, 1)
      STEPG(ip + 1, 1, 1)
    }

    const float l_tot = l_run + __shfl_xor(l_run, 32);
    const float inv = 1.0f / l_tot;
    float* op = Ob + (size_t)(qb + ln) * HE;
    #pragma unroll
    for (int dt = 0; dt < 2; ++dt)
      #pragma unroll
      for (int rq = 0; rq < 4; ++rq) {
        f32x4 w;
        w[0]=(oacc2[0][dt][rq*4+0]+oacc2[1][dt][rq*4+0])*inv;
        w[1]=(oacc2[0][dt][rq*4+1]+oacc2[1][dt][rq*4+1])*inv;
        w[2]=(oacc2[0][dt][rq*4+2]+oacc2[1][dt][rq*4+2])*inv;
        w[3]=(oacc2[0][dt][rq*4+3]+oacc2[1][dt][rq*4+3])*inv;
        *(f32x4*)(op + dt*32 + 8*rq + 4*hi) = w;
      }
  }
}

// ---------------- last-resort fused fallback (R6-style) ----------------
__global__ __launch_bounds__(256, 3) void fa_fwd_fused(
    const float* __restrict__ Q, const float* __restrict__ K,
    const float* __restrict__ V, float* __restrict__ O)
{
  __shared__ unsigned char k_lds[2][64*128];
  __shared__ unsigned char v_lds[2][64*128];
  const int tid  = threadIdx.x;
  const int lane = tid & 63;
  const int wid  = tid >> 6;
  const int hi   = lane >> 5;
  const int ln   = lane & 31;
  const int trow = tid >> 4;
  const int tcol = (tid & 15) * 4;
  const int sq   = trow * 4;
  const int bidp = blockIdx.x;
  const int lb   = (bidp & 7) * 64 + (bidp >> 3);
  const int pair = lb & 7;
  const int bh   = lb >> 3;
  const int h    = bh & (NH-1);
  const int b    = bh >> 4;
  const size_t base = ((size_t)b * NL * NH + h) * NE;
  const float* Qb = Q + base;
  const float* Kb = K + base;
  const float* Vb = V + base;
  float*       Ob = O + base;
  int cur = 0;
  #pragma unroll 1
  for (int hf = 0; hf < 2; ++hf) {
    const int qt = hf ? (NQT - 1 - pair) : pair;
    const int q0 = qt * QBLK;
    const int qb = q0 + wid * QW;
    const int nt = qt * 2 + 2;
    const int qg = qb + ln;
    bf16x8 qf[4];
    {
      const float* qp = Qb + (size_t)(qb + ln) * HE + hi * 8;
      #pragma unroll
      for (int ks = 0; ks < 4; ++ks) {
        f32x4 a0 = *(const f32x4*)(qp + ks*16);
        f32x4 a1 = *(const f32x4*)(qp + ks*16 + 4);
        union { unsigned u[4]; bf16x8 v; } f;
        f.u[0] = pk2(a0[0]*QSCALE, a0[1]*QSCALE);
        f.u[1] = pk2(a0[2]*QSCALE, a0[3]*QSCALE);
        f.u[2] = pk2(a1[0]*QSCALE, a1[1]*QSCALE);
        f.u[3] = pk2(a1[2]*QSCALE, a1[3]*QSCALE);
        qf[ks] = f.v;
      }
    }
    f32x16 oacc[2];
    oacc[0] = (f32x16)0.0f; oacc[1] = (f32x16)0.0f;
    float l_run = 0.0f;
    f32x4 kreg[4], vreg[4];
    #pragma unroll
    for (int p = 0; p < 4; ++p)
      kreg[p] = *(const f32x4*)(Kb + (size_t)(trow + p*16) * HE + tcol);
    #pragma unroll
    for (int i = 0; i < 4; ++i)
      vreg[i] = *(const f32x4*)(Vb + (size_t)(sq + i) * HE + tcol);
    #pragma unroll 1
    for (int it = 0; it < nt; ++it) {
      unsigned char* kb = k_lds[cur];
      unsigned char* vb = v_lds[cur];
      #pragma unroll
      for (int p = 0; p < 4; ++p) {
        const int row = trow + p*16;
        union { unsigned u[2]; bf16x4 v; } w;
        w.u[0] = pk2(kreg[p][0], kreg[p][1]);
        w.u[1] = pk2(kreg[p][2], kreg[p][3]);
        *(bf16x4*)(kb + SWZ(row, tcol*2)) = w.v;
      }
      #pragma unroll
      for (int j = 0; j < 4; ++j) {
        const int er = tcol + j;
        union { unsigned u[2]; bf16x4 v; } w;
        w.u[0] = pk2(vreg[0][j], vreg[1][j]);
        w.u[1] = pk2(vreg[2][j], vreg[3][j]);
        *(bf16x4*)(vb + SWZ(er, sq*2)) = w.v;
      }
      if (it + 1 < nt) {
        const int s0 = (it + 1) * 64;
        #pragma unroll
        for (int p = 0; p < 4; ++p)
          kreg[p] = *(const f32x4*)(Kb + (size_t)(s0 + trow + p*16) * HE + tcol);
        #pragma unroll
        for (int i = 0; i < 4; ++i)
          vreg[i] = *(const f32x4*)(Vb + (size_t)(s0 + sq + i) * HE + tcol);
      }
      asm volatile("s_waitcnt lgkmcnt(0)" ::: "memory");
      __builtin_amdgcn_sched_barrier(0);
      __builtin_amdgcn_s_barrier();
      __builtin_amdgcn_sched_barrier(0);
      #pragma unroll
      for (int sub = 0; sub < 2; ++sub) {
        const int kv0s = it*64 + sub*32;
        if (kv0s <= qb + QW - 1) {
          f32x16 sc = (f32x16)0.0f;
          #pragma unroll
          for (int ks = 0; ks < 4; ++ks) {
            const int kvr = sub*32 + ln;
            bf16x8 af = *(const bf16x8*)(kb + SWZ(kvr, ks*32 + hi*16));
            sc = __builtin_amdgcn_mfma_f32_32x32x16_bf16(af, qf[ks], sc, 0, 0, 0);
          }
          if (kv0s + 31 > qb) {
            #pragma unroll
            for (int r = 0; r < 16; ++r) {
              const int kvg = kv0s + (r&3) + 8*(r>>2) + 4*hi;
              sc[r] = (kvg > qg) ? 0.0f : exp2f(sc[r]);
            }
          } else {
            #pragma unroll
            for (int r = 0; r < 16; ++r) sc[r] = exp2f(sc[r]);
          }
          float s0_ = (sc[0]+sc[1])+(sc[2]+sc[3]);
          float s1_ = (sc[4]+sc[5])+(sc[6]+sc[7]);
          float s2_ = (sc[8]+sc[9])+(sc[10]+sc[11]);
          float s3_ = (sc[12]+sc[13])+(sc[14]+sc[15]);
          l_run += (s0_+s1_)+(s2_+s3_);
          unsigned c0 = pk2(sc[0],sc[1]),   c1 = pk2(sc[2],sc[3]);
          unsigned c2 = pk2(sc[4],sc[5]),   c3 = pk2(sc[6],sc[7]);
          unsigned c4 = pk2(sc[8],sc[9]),   c5 = pk2(sc[10],sc[11]);
          unsigned c6 = pk2(sc[12],sc[13]), c7 = pk2(sc[14],sc[15]);
          pswap(c0, c2);  pswap(c1, c3);
          pswap(c4, c6);  pswap(c5, c7);
          union { unsigned u[4]; bf16x8 v; } pa0, pa1;
          pa0.u[0]=c0; pa0.u[1]=c1; pa0.u[2]=c2; pa0.u[3]=c3;
          pa1.u[0]=c4; pa1.u[1]=c5; pa1.u[2]=c6; pa1.u[3]=c7;
          #pragma unroll
          for (int dt = 0; dt < 2; ++dt) {
            const int dr = dt*32 + ln;
            #pragma unroll
            for (int ks2 = 0; ks2 < 2; ++ks2) {
              bf16x8 av = *(const bf16x8*)(vb + SWZ(dr, sub*64 + ks2*32 + hi*16));
              oacc[dt] = __builtin_amdgcn_mfma_f32_32x32x16_bf16(
                  av, ks2 ? pa1.v : pa0.v, oacc[dt], 0, 0, 0);
            }
          }
        }
      }
      cur ^= 1;
    }
    const float l_tot = l_run + __shfl_xor(l_run, 32);
    const float inv = 1.0f / l_tot;
    float* op = Ob + (size_t)(qb + ln) * HE;
    #pragma unroll
    for (int dt = 0; dt < 2; ++dt)
      #pragma unroll
      for (int rq = 0; rq < 4; ++rq) {
        f32x4 w;
        w[0]=oacc[dt][rq*4+0]*inv; w[1]=oacc[dt][rq*4+1]*inv;
        w[2]=oacc[dt][rq*4+2]*inv; w[3]=oacc[dt][rq*4+3]*inv;
        *(f32x4*)(op + dt*32 + 8*rq + 4*hi) = w;
      }
  }
}

extern "C" void kernel_launch(void* const* d_in, const int* in_sizes, int n_in,
                              void* d_out, int out_size, void* d_ws, size_t ws_size,
                              hipStream_t stream) {
  const float* Q = (const float*)d_in[0];
  const float* K = (const float*)d_in[1];
  const float* V = (const float*)d_in[2];
  float* O = (float*)d_out;
  unsigned char* ws = (unsigned char*)d_ws;
  if (ws_size >= WS_SPLIT) {
    fa_stage<<<dim3(NBH * NKT), dim3(256), 0, stream>>>(K, V, ws);
    fa_split<<<dim3(NB * NH * NPAIR * 2), dim3(256), 0, stream>>>(
        Q, ws, (unsigned short*)(ws + IMG_BYTES),
        (float*)(ws + IMG_BYTES + 2*OPART_HALF));
    fa_merge<<<dim3((NB * NL * NH * NE / 4) / 256), dim3(256), 0, stream>>>(
        (const unsigned short*)(ws + IMG_BYTES),
        (const float*)(ws + IMG_BYTES + 2*OPART_HALF), O);
  } else if (ws_size >= WS_NEED) {
    fa_stage<<<dim3(NBH * NKT), dim3(256), 0, stream>>>(K, V, ws);
    fa_fwd<<<dim3(NB * NH * NPAIR), dim3(256), 0, stream>>>(Q, ws, O);
  } else {
    fa_fwd_fused<<<dim3(NB * NH * NPAIR), dim3(256), 0, stream>>>(Q, K, V, O);
  }
}

// Round 15
// 85.849 us; speedup vs baseline: 1.2168x; 1.2168x over previous
//
#include <hip/hip_runtime.h>
#include <hip/hip_bf16.h>

typedef __attribute__((ext_vector_type(8))) short bf16x8;
typedef __attribute__((ext_vector_type(4))) short bf16x4;
typedef __attribute__((ext_vector_type(4))) float f32x4;
typedef __attribute__((ext_vector_type(16))) float f32x16;

#define NB 4
#define NL 2048
#define NH 16
#define NE 64
#define HE (NH*NE)
#define QW 32
#define QBLK 128
#define NQT (NL/QBLK)      // 16
#define NPAIR (NQT/2)      // 8
#define NBH 64
#define NKT 32             // kv64 tiles per (b,h)
#define TILE_IMG 16384     // 8KB K + 8KB V^T per (bh, kv-tile)
#define WS_NEED ((size_t)NBH * NKT * TILE_IMG)   // 32 MB
#define QSCALE (0.125f * 1.44269504088896340736f)  // 1/sqrt(64) * log2(e)

__device__ __forceinline__ unsigned pk2(float a, float b) {
  float2 t; t.x = a; t.y = b;
  __hip_bfloat162 hh = __float22bfloat162_rn(t);    // v_cvt_pk_bf16_f32
  union { __hip_bfloat162 h; unsigned u; } v; v.h = hh;
  return v.u;                                        // a lo16, b hi16
}
__device__ __forceinline__ void pswap(unsigned &a, unsigned &b) {
  auto r = __builtin_amdgcn_permlane32_swap(a, b, false, false);
  a = r[0]; b = r[1];
}
#define SWZ(row,col) ((row)*128 + ((col) ^ ((((row) ^ ((row)>>2)) & 7) << 4)))

__device__ __forceinline__ void cp16(unsigned char* lds, const unsigned char* g) {
  __builtin_amdgcn_global_load_lds(
      (const __attribute__((address_space(1))) unsigned int*)g,
      (__attribute__((address_space(3))) unsigned int*)lds, 16, 0, 0);
}

// ---------------- prologue: build bf16 staged tile images in ws ----------------
__global__ __launch_bounds__(256) void fa_stage(
    const float* __restrict__ K, const float* __restrict__ V,
    unsigned char* __restrict__ img)
{
  const int tid = threadIdx.x;
  const int bid = blockIdx.x;
  const int bh  = bid >> 5;
  const int t0  = bid & 31;
  const int h = bh & (NH-1), b = bh >> 4;
  const size_t base = ((size_t)b * NL * NH + h) * NE + (size_t)(t0 * 64) * HE;
  unsigned char* kimg = img + (size_t)(bh * NKT + t0) * TILE_IMG;
  unsigned char* vimg = kimg + 8192;
  #pragma unroll
  for (int rep = 0; rep < 2; ++rep) {
    const int idx = rep * 256 + tid;
    const int row = idx >> 3, gr = idx & 7;
    const float* kp = K + base + (size_t)row * HE + gr * 8;
    f32x4 a0 = *(const f32x4*)kp;
    f32x4 a1 = *(const f32x4*)(kp + 4);
    union { unsigned u[4]; bf16x8 v; } w;
    w.u[0] = pk2(a0[0], a0[1]); w.u[1] = pk2(a0[2], a0[3]);
    w.u[2] = pk2(a1[0], a1[1]); w.u[3] = pk2(a1[2], a1[3]);
    *(bf16x8*)(kimg + SWZ(row, gr * 16)) = w.v;
  }
  const int trow = tid >> 4, tcol = (tid & 15) * 4, sq = trow * 4;
  f32x4 vr[4];
  #pragma unroll
  for (int i = 0; i < 4; ++i)
    vr[i] = *(const f32x4*)(V + base + (size_t)(sq + i) * HE + tcol);
  #pragma unroll
  for (int j = 0; j < 4; ++j) {
    const int er = tcol + j;
    union { unsigned u[2]; bf16x4 v; } w;
    w.u[0] = pk2(vr[0][j], vr[1][j]);
    w.u[1] = pk2(vr[2][j], vr[3][j]);
    *(bf16x4*)(vimg + SWZ(er, sq * 2)) = w.v;
  }
}

#define PACK(SC, PA0, PA1)                                                     \
      l_run += (((SC[0]+SC[1])+(SC[2]+SC[3]))+((SC[4]+SC[5])+(SC[6]+SC[7])))   \
             + (((SC[8]+SC[9])+(SC[10]+SC[11]))+((SC[12]+SC[13])+(SC[14]+SC[15])));\
      {                                                                        \
        unsigned c0 = pk2(SC[0],SC[1]),   c1 = pk2(SC[2],SC[3]);               \
        unsigned c2 = pk2(SC[4],SC[5]),   c3 = pk2(SC[6],SC[7]);               \
        unsigned c4 = pk2(SC[8],SC[9]),   c5 = pk2(SC[10],SC[11]);             \
        unsigned c6 = pk2(SC[12],SC[13]), c7 = pk2(SC[14],SC[15]);             \
        pswap(c0, c2);  pswap(c1, c3);                                         \
        pswap(c4, c6);  pswap(c5, c7);                                         \
        PA0.u[0]=c0; PA0.u[1]=c1; PA0.u[2]=c2; PA0.u[3]=c3;                    \
        PA1.u[0]=c4; PA1.u[1]=c5; PA1.u[2]=c6; PA1.u[3]=c7;                    \
      }

#define SMPACK(SC, PA0, PA1)                                                   \
      _Pragma("unroll")                                                        \
      for (int r = 0; r < 16; ++r) SC[r] = exp2f(SC[r]);                       \
      PACK(SC, PA0, PA1)

// one kv64 step; tile IT lives in buf IT&3; issues tile IT+2 into (BUF+2)&3;
// steady-state wait = vmcnt(4): keep next tile's 4 loads in flight (T4).
#define STEP(IT, BUF)                                                          \
    {                                                                          \
      if ((IT) + 1 < nt) { asm volatile("s_waitcnt vmcnt(4)" ::: "memory"); }  \
      else               { asm volatile("s_waitcnt vmcnt(0)" ::: "memory"); }  \
      __builtin_amdgcn_sched_barrier(0);                                       \
      __builtin_amdgcn_s_barrier();                                            \
      __builtin_amdgcn_sched_barrier(0);                                       \
      if ((IT) + 2 < nt) {                                                     \
        unsigned char* kd = &k_lds[((BUF)+2)&3][0];                            \
        unsigned char* vd = &v_lds[((BUF)+2)&3][0];                            \
        cp16(kd + wb,        src_pf);                                          \
        cp16(kd + 4096 + wb, src_pf + 4096);                                   \
        cp16(vd + wb,        src_pf + 8192);                                   \
        cp16(vd + 4096 + wb, src_pf + 12288);                                  \
        src_pf += TILE_IMG;                                                    \
      }                                                                        \
      const int kv0 = (IT)*64;                                                 \
      if (kv0 + 63 <= qb) {                                                    \
        f32x16 sc0 = (f32x16)0.0f, sc1 = (f32x16)0.0f;                         \
        _Pragma("unroll")                                                      \
        for (int ks = 0; ks < 4; ++ks) {                                       \
          bf16x8 af0 = *(const bf16x8*)(&k_lds[BUF][0] + addr4[ks]);           \
          bf16x8 af1 = *(const bf16x8*)(&k_lds[BUF][0] + addr4[ks] + 4096);    \
          sc0 = __builtin_amdgcn_mfma_f32_32x32x16_bf16(af0, qf[ks], sc0,0,0,0);\
          sc1 = __builtin_amdgcn_mfma_f32_32x32x16_bf16(af1, qf[ks], sc1,0,0,0);\
        }                                                                      \
        union { unsigned u[4]; bf16x8 v; } a00, a01, a10, a11;                 \
        SMPACK(sc0, a00, a01)                                                  \
        SMPACK(sc1, a10, a11)                                                  \
        _Pragma("unroll")                                                      \
        for (int dt = 0; dt < 2; ++dt) {                                       \
          bf16x8 v00 = *(const bf16x8*)(&v_lds[BUF][0] + addr4[0] + dt*4096);  \
          bf16x8 v01 = *(const bf16x8*)(&v_lds[BUF][0] + addr4[1] + dt*4096);  \
          bf16x8 v10 = *(const bf16x8*)(&v_lds[BUF][0] + addr4[2] + dt*4096);  \
          bf16x8 v11 = *(const bf16x8*)(&v_lds[BUF][0] + addr4[3] + dt*4096);  \
          oacc2[0][dt] = __builtin_amdgcn_mfma_f32_32x32x16_bf16(              \
              v00, a00.v, oacc2[0][dt], 0, 0, 0);                              \
          oacc2[1][dt] = __builtin_amdgcn_mfma_f32_32x32x16_bf16(              \
              v10, a10.v, oacc2[1][dt], 0, 0, 0);                              \
          oacc2[0][dt] = __builtin_amdgcn_mfma_f32_32x32x16_bf16(              \
              v01, a01.v, oacc2[0][dt], 0, 0, 0);                              \
          oacc2[1][dt] = __builtin_amdgcn_mfma_f32_32x32x16_bf16(              \
              v11, a11.v, oacc2[1][dt], 0, 0, 0);                              \
        }                                                                      \
      } else {                                                                 \
        _Pragma("unroll")                                                      \
        for (int sub = 0; sub < 2; ++sub) {                                    \
          const int kv0s = kv0 + sub*32;                                       \
          if (kv0s <= qb + QW - 1) {                                           \
            f32x16 sc = (f32x16)0.0f;                                          \
            _Pragma("unroll")                                                  \
            for (int ks = 0; ks < 4; ++ks) {                                   \
              bf16x8 af = *(const bf16x8*)(&k_lds[BUF][0] + addr4[ks] + sub*4096);\
              sc = __builtin_amdgcn_mfma_f32_32x32x16_bf16(af, qf[ks], sc,0,0,0);\
            }                                                                  \
            _Pragma("unroll")                                                  \
            for (int r = 0; r < 16; ++r) {                                     \
              const int kvg = kv0s + (r&3) + 8*(r>>2) + 4*hi;                  \
              sc[r] = (kvg > qg) ? 0.0f : exp2f(sc[r]);                        \
            }                                                                  \
            union { unsigned u[4]; bf16x8 v; } pa0, pa1;                       \
            PACK(sc, pa0, pa1)                                                 \
            _Pragma("unroll")                                                  \
            for (int dt = 0; dt < 2; ++dt) {                                   \
              _Pragma("unroll")                                                \
              for (int ks2 = 0; ks2 < 2; ++ks2) {                              \
                bf16x8 av = *(const bf16x8*)(&v_lds[BUF][0] +                  \
                    addr4[sub*2 + ks2] + dt*4096);                             \
                oacc2[sub][dt] = __builtin_amdgcn_mfma_f32_32x32x16_bf16(      \
                    av, ks2 ? pa1.v : pa0.v, oacc2[sub][dt], 0, 0, 0);         \
              }                                                                \
            }                                                                  \
          }                                                                    \
        }                                                                      \
      }                                                                        \
    }

#define QTILE_SETUP()                                                          \
    bf16x8 qf[4];                                                              \
    {                                                                          \
      const float* qp = Qb + (size_t)(qb + ln) * HE + hi * 8;                  \
      _Pragma("unroll")                                                        \
      for (int ks = 0; ks < 4; ++ks) {                                         \
        f32x4 a0 = *(const f32x4*)(qp + ks*16);                                \
        f32x4 a1 = *(const f32x4*)(qp + ks*16 + 4);                            \
        union { unsigned u[4]; bf16x8 v; } f;                                  \
        f.u[0] = pk2(a0[0]*QSCALE, a0[1]*QSCALE);                              \
        f.u[1] = pk2(a0[2]*QSCALE, a0[3]*QSCALE);                              \
        f.u[2] = pk2(a1[0]*QSCALE, a1[1]*QSCALE);                              \
        f.u[3] = pk2(a1[2]*QSCALE, a1[3]*QSCALE);                              \
        qf[ks] = f.v;                                                          \
      }                                                                        \
    }                                                                          \
    f32x16 oacc2[2][2];                                                        \
    oacc2[0][0] = (f32x16)0.0f; oacc2[0][1] = (f32x16)0.0f;                    \
    oacc2[1][0] = (f32x16)0.0f; oacc2[1][1] = (f32x16)0.0f;                    \
    float l_run = 0.0f;

// ---------------- main: deep-pipelined flash attention from images ----------------
__global__ __launch_bounds__(256, 2) void fa_fwd(
    const float* __restrict__ Q, const unsigned char* __restrict__ img,
    float* __restrict__ O)
{
  __shared__ unsigned char k_lds[4][8192];   // 4-buffer ring (2-ahead prefetch)
  __shared__ unsigned char v_lds[4][8192];

  const int tid  = threadIdx.x;
  const int lane = tid & 63;
  const int wid  = tid >> 6;
  const int hi   = lane >> 5;
  const int ln   = lane & 31;

  const int bidp = blockIdx.x;
  const int lb   = (bidp & 7) * 64 + (bidp >> 3);
  const int pair = lb & 7;
  const int bh   = lb >> 3;
  const int h    = bh & (NH-1);
  const int b    = bh >> 4;

  const size_t base = ((size_t)b * NL * NH + h) * NE;
  const float* Qb = Q + base;
  float*       Ob = O + base;
  const unsigned char* bimg = img + (size_t)bh * NKT * TILE_IMG;

  int addr4[4];
  {
    const int F = ((ln ^ (ln >> 2)) & 7) << 4;
    #pragma unroll
    for (int j = 0; j < 4; ++j) addr4[j] = ln*128 + ((j*32 + hi*16) ^ F);
  }
  const int wb = wid << 10;

  #pragma unroll 1
  for (int hf = 0; hf < 2; ++hf) {
    const int qt = hf ? (NQT - 1 - pair) : pair;   // paired: 34 steps/block
    const int q0 = qt * QBLK;
    const int qb = q0 + wid * QW;
    const int nt = qt * 2 + 2;                     // even, >= 2
    const int qg = qb + ln;

    QTILE_SETUP()

    // clean vmcnt baseline (Q loads / prev-hf stores drained), then protect
    // LDS reuse across hf before prologue writes buf0/buf1.
    asm volatile("s_waitcnt vmcnt(0)" ::: "memory");
    __builtin_amdgcn_sched_barrier(0);
    __builtin_amdgcn_s_barrier();
    const unsigned char* src_pf = bimg + (size_t)tid * 16;
    cp16(&k_lds[0][0] + wb,        src_pf);
    cp16(&k_lds[0][0] + 4096 + wb, src_pf + 4096);
    cp16(&v_lds[0][0] + wb,        src_pf + 8192);
    cp16(&v_lds[0][0] + 4096 + wb, src_pf + 12288);
    src_pf += TILE_IMG;
    cp16(&k_lds[1][0] + wb,        src_pf);
    cp16(&k_lds[1][0] + 4096 + wb, src_pf + 4096);
    cp16(&v_lds[1][0] + wb,        src_pf + 8192);
    cp16(&v_lds[1][0] + 4096 + wb, src_pf + 12288);
    src_pf += TILE_IMG;

    int bs = 0;
    #pragma unroll 1
    for (; bs + 4 <= nt; bs += 4) {
      STEP(bs + 0, 0)
      STEP(bs + 1, 1)
      STEP(bs + 2, 2)
      STEP(bs + 3, 3)
    }
    if (bs < nt) {            // nt % 4 == 2 tail; buffers 0,1 (bs % 4 == 0)
      STEP(bs + 0, 0)
      STEP(bs + 1, 1)
    }

    const float l_tot = l_run + __shfl_xor(l_run, 32);
    const float inv = 1.0f / l_tot;
    float* op = Ob + (size_t)(qb + ln) * HE;
    #pragma unroll
    for (int dt = 0; dt < 2; ++dt)
      #pragma unroll
      for (int rq = 0; rq < 4; ++rq) {
        f32x4 w;
        w[0]=(oacc2[0][dt][rq*4+0]+oacc2[1][dt][rq*4+0])*inv;
        w[1]=(oacc2[0][dt][rq*4+1]+oacc2[1][dt][rq*4+1])*inv;
        w[2]=(oacc2[0][dt][rq*4+2]+oacc2[1][dt][rq*4+2])*inv;
        w[3]=(oacc2[0][dt][rq*4+3]+oacc2[1][dt][rq*4+3])*inv;
        *(f32x4*)(op + dt*32 + 8*rq + 4*hi) = w;
      }
  }
}

// ---------------- fused fallback (R6-style) if ws too small ----------------
__global__ __launch_bounds__(256, 3) void fa_fwd_fused(
    const float* __restrict__ Q, const float* __restrict__ K,
    const float* __restrict__ V, float* __restrict__ O)
{
  __shared__ unsigned char kf_lds[2][64*128];
  __shared__ unsigned char vf_lds[2][64*128];
  const int tid  = threadIdx.x;
  const int lane = tid & 63;
  const int wid  = tid >> 6;
  const int hi   = lane >> 5;
  const int ln   = lane & 31;
  const int trow = tid >> 4;
  const int tcol = (tid & 15) * 4;
  const int sq   = trow * 4;
  const int bidp = blockIdx.x;
  const int lb   = (bidp & 7) * 64 + (bidp >> 3);
  const int pair = lb & 7;
  const int bh   = lb >> 3;
  const int h    = bh & (NH-1);
  const int b    = bh >> 4;
  const size_t base = ((size_t)b * NL * NH + h) * NE;
  const float* Qb = Q + base;
  const float* Kb = K + base;
  const float* Vb = V + base;
  float*       Ob = O + base;
  int cur = 0;
  #pragma unroll 1
  for (int hf = 0; hf < 2; ++hf) {
    const int qt = hf ? (NQT - 1 - pair) : pair;
    const int q0 = qt * QBLK;
    const int qb = q0 + wid * QW;
    const int nt = qt * 2 + 2;
    const int qg = qb + ln;
    bf16x8 qf[4];
    {
      const float* qp = Qb + (size_t)(qb + ln) * HE + hi * 8;
      #pragma unroll
      for (int ks = 0; ks < 4; ++ks) {
        f32x4 a0 = *(const f32x4*)(qp + ks*16);
        f32x4 a1 = *(const f32x4*)(qp + ks*16 + 4);
        union { unsigned u[4]; bf16x8 v; } f;
        f.u[0] = pk2(a0[0]*QSCALE, a0[1]*QSCALE);
        f.u[1] = pk2(a0[2]*QSCALE, a0[3]*QSCALE);
        f.u[2] = pk2(a1[0]*QSCALE, a1[1]*QSCALE);
        f.u[3] = pk2(a1[2]*QSCALE, a1[3]*QSCALE);
        qf[ks] = f.v;
      }
    }
    f32x16 oacc[2];
    oacc[0] = (f32x16)0.0f; oacc[1] = (f32x16)0.0f;
    float l_run = 0.0f;
    f32x4 kreg[4], vreg[4];
    #pragma unroll
    for (int p = 0; p < 4; ++p)
      kreg[p] = *(const f32x4*)(Kb + (size_t)(trow + p*16) * HE + tcol);
    #pragma unroll
    for (int i = 0; i < 4; ++i)
      vreg[i] = *(const f32x4*)(Vb + (size_t)(sq + i) * HE + tcol);
    #pragma unroll 1
    for (int it = 0; it < nt; ++it) {
      unsigned char* kb = kf_lds[cur];
      unsigned char* vb = vf_lds[cur];
      #pragma unroll
      for (int p = 0; p < 4; ++p) {
        const int row = trow + p*16;
        union { unsigned u[2]; bf16x4 v; } w;
        w.u[0] = pk2(kreg[p][0], kreg[p][1]);
        w.u[1] = pk2(kreg[p][2], kreg[p][3]);
        *(bf16x4*)(kb + SWZ(row, tcol*2)) = w.v;
      }
      #pragma unroll
      for (int j = 0; j < 4; ++j) {
        const int er = tcol + j;
        union { unsigned u[2]; bf16x4 v; } w;
        w.u[0] = pk2(vreg[0][j], vreg[1][j]);
        w.u[1] = pk2(vreg[2][j], vreg[3][j]);
        *(bf16x4*)(vb + SWZ(er, sq*2)) = w.v;
      }
      if (it + 1 < nt) {
        const int s0 = (it + 1) * 64;
        #pragma unroll
        for (int p = 0; p < 4; ++p)
          kreg[p] = *(const f32x4*)(Kb + (size_t)(s0 + trow + p*16) * HE + tcol);
        #pragma unroll
        for (int i = 0; i < 4; ++i)
          vreg[i] = *(const f32x4*)(Vb + (size_t)(s0 + sq + i) * HE + tcol);
      }
      asm volatile("s_waitcnt lgkmcnt(0)" ::: "memory");
      __builtin_amdgcn_sched_barrier(0);
      __builtin_amdgcn_s_barrier();
      __builtin_amdgcn_sched_barrier(0);
      #pragma unroll
      for (int sub = 0; sub < 2; ++sub) {
        const int kv0s = it*64 + sub*32;
        if (kv0s <= qb + QW - 1) {
          f32x16 sc = (f32x16)0.0f;
          #pragma unroll
          for (int ks = 0; ks < 4; ++ks) {
            const int kvr = sub*32 + ln;
            bf16x8 af = *(const bf16x8*)(kb + SWZ(kvr, ks*32 + hi*16));
            sc = __builtin_amdgcn_mfma_f32_32x32x16_bf16(af, qf[ks], sc, 0, 0, 0);
          }
          if (kv0s + 31 > qb) {
            #pragma unroll
            for (int r = 0; r < 16; ++r) {
              const int kvg = kv0s + (r&3) + 8*(r>>2) + 4*hi;
              sc[r] = (kvg > qg) ? 0.0f : exp2f(sc[r]);
            }
          } else {
            #pragma unroll
            for (int r = 0; r < 16; ++r) sc[r] = exp2f(sc[r]);
          }
          float s0_ = (sc[0]+sc[1])+(sc[2]+sc[3]);
          float s1_ = (sc[4]+sc[5])+(sc[6]+sc[7]);
          float s2_ = (sc[8]+sc[9])+(sc[10]+sc[11]);
          float s3_ = (sc[12]+sc[13])+(sc[14]+sc[15]);
          l_run += (s0_+s1_)+(s2_+s3_);
          unsigned c0 = pk2(sc[0],sc[1]),   c1 = pk2(sc[2],sc[3]);
          unsigned c2 = pk2(sc[4],sc[5]),   c3 = pk2(sc[6],sc[7]);
          unsigned c4 = pk2(sc[8],sc[9]),   c5 = pk2(sc[10],sc[11]);
          unsigned c6 = pk2(sc[12],sc[13]), c7 = pk2(sc[14],sc[15]);
          pswap(c0, c2);  pswap(c1, c3);
          pswap(c4, c6);  pswap(c5, c7);
          union { unsigned u[4]; bf16x8 v; } pa0, pa1;
          pa0.u[0]=c0; pa0.u[1]=c1; pa0.u[2]=c2; pa0.u[3]=c3;
          pa1.u[0]=c4; pa1.u[1]=c5; pa1.u[2]=c6; pa1.u[3]=c7;
          #pragma unroll
          for (int dt = 0; dt < 2; ++dt) {
            const int dr = dt*32 + ln;
            #pragma unroll
            for (int ks2 = 0; ks2 < 2; ++ks2) {
              bf16x8 av = *(const bf16x8*)(vb + SWZ(dr, sub*64 + ks2*32 + hi*16));
              oacc[dt] = __builtin_amdgcn_mfma_f32_32x32x16_bf16(
                  av, ks2 ? pa1.v : pa0.v, oacc[dt], 0, 0, 0);
            }
          }
        }
      }
      cur ^= 1;
    }
    const float l_tot = l_run + __shfl_xor(l_run, 32);
    const float inv = 1.0f / l_tot;
    float* op = Ob + (size_t)(qb + ln) * HE;
    #pragma unroll
    for (int dt = 0; dt < 2; ++dt)
      #pragma unroll
      for (int rq = 0; rq < 4; ++rq) {
        f32x4 w;
        w[0]=oacc[dt][rq*4+0]*inv; w[1]=oacc[dt][rq*4+1]*inv;
        w[2]=oacc[dt][rq*4+2]*inv; w[3]=oacc[dt][rq*4+3]*inv;
        *(f32x4*)(op + dt*32 + 8*rq + 4*hi) = w;
      }
  }
}

extern "C" void kernel_launch(void* const* d_in, const int* in_sizes, int n_in,
                              void* d_out, int out_size, void* d_ws, size_t ws_size,
                              hipStream_t stream) {
  const float* Q = (const float*)d_in[0];
  const float* K = (const float*)d_in[1];
  const float* V = (const float*)d_in[2];
  float* O = (float*)d_out;
  if (ws_size >= WS_NEED) {
    fa_stage<<<dim3(NBH * NKT), dim3(256), 0, stream>>>(K, V, (unsigned char*)d_ws);
    fa_fwd<<<dim3(NB * NH * NPAIR), dim3(256), 0, stream>>>(
        Q, (const unsigned char*)d_ws, O);
  } else {
    fa_fwd_fused<<<dim3(NB * NH * NPAIR), dim3(256), 0, stream>>>(Q, K, V, O);
  }
}